// Round 1
// baseline (4175.472 us; speedup 1.0000x reference)
//
#include <hip/hip_runtime.h>
#include <hip/hip_bf16.h>

#define T_DIM 256
#define B_DIM 256
#define E_DIM 256
#define H_DIM 512
#define V_DIM 50257
#define KTOT  768   // E + H

typedef __attribute__((ext_vector_type(8))) short short8;
typedef __attribute__((ext_vector_type(4))) float f32x4;

__device__ __forceinline__ unsigned short f2bf(float f) {
    union { float f; unsigned u; } v; v.f = f;
    unsigned r = v.u + 0x7FFFu + ((v.u >> 16) & 1u);
    return (unsigned short)(r >> 16);
}
__device__ __forceinline__ float sigmoidf_(float x) {
    return 1.0f / (1.0f + __expf(-x));
}
__device__ __forceinline__ float tanhf_(float x) {
    float xc = fminf(fmaxf(x, -15.0f), 15.0f);
    float e = __expf(2.0f * xc);
    return (e - 1.0f) / (e + 1.0f);
}

// ---------------- LSTM persistent kernel ----------------
// 256 blocks = 8 batch-groups (32 rows) x 32 hidden-groups (16 cols).
// 128 threads = 2 waves; wave w handles batch rows [bb+w*16, +16).
// Each wave: 4 gate tiles [16,16], K=768 -> 24 k-tiles -> 96 MFMA/step.
// Weights slice [768, 4x16] pre-staged in LDS as B-fragments (96 KiB).
__global__ void __launch_bounds__(128, 1)
lstm_persist(const float* __restrict__ x,
             const float* __restrict__ wk,
             const float* __restrict__ bias,
             unsigned short* __restrict__ hbuf,   // [2][B][H] bf16
             int* __restrict__ bar)               // 8 counters, stride 32 ints
{
    extern __shared__ unsigned short lds_w[];     // [96 frag][64 lane][8]
    const int tid = threadIdx.x;
    const int blk = blockIdx.x;
    const int bg  = blk & 7;          // batch group  (heuristic: same-XCD)
    const int hg  = blk >> 3;         // hidden group
    const int bb  = bg * 32;
    const int hh  = hg * 16;

    // ---- preload weights into LDS in B-frag layout ----
    // frag f = kt*4+g ; lane = hi*16+c ; elem j : global k=kt*32+hi*8+j, col=g*512+hh+c
    for (int f = 0; f < 96; ++f) {
        const int kt = f >> 2, g = f & 3;
        for (int idx = tid; idx < 512; idx += 128) {
            const int c  = idx & 15;
            const int hi = (idx >> 4) & 3;
            const int j  = idx >> 6;
            const int k  = kt * 32 + hi * 8 + j;
            const int col = g * 512 + hh + c;
            lds_w[(f * 64 + hi * 16 + c) * 8 + j] = f2bf(wk[(size_t)k * 2048 + col]);
        }
    }
    __syncthreads();

    const int w    = tid >> 6;        // wave = M-half
    const int lane = tid & 63;
    const int lc   = lane & 15;
    const int lk   = lane >> 4;

    const float bi = bias[0 * 512 + hh + lc];
    const float bj = bias[1 * 512 + hh + lc];
    const float bf_ = bias[2 * 512 + hh + lc] + 1.0f;   // FORGET_BIAS
    const float bo = bias[3 * 512 + hh + lc];

    f32x4 c_frag = {0.f, 0.f, 0.f, 0.f};

    const int arow = bb + w * 16 + lc;                 // A-frag row (load side)
    const int orow = bb + w * 16 + lk * 4;             // C-frag row base (store side)
    const float* xbase = x + (size_t)arow * E_DIM + lk * 8;

    for (int t = 0; t < T_DIM; ++t) {
        const unsigned short* hr = hbuf + (size_t)(t & 1) * (B_DIM * H_DIM)
                                        + (size_t)arow * H_DIM + lk * 8;
        const float* xr = xbase + (size_t)t * (B_DIM * E_DIM);

        f32x4 a0 = {0.f,0.f,0.f,0.f}, a1 = a0, a2 = a0, a3 = a0;

        #pragma unroll
        for (int kt = 0; kt < 8; ++kt) {               // x part (fp32 -> bf16)
            const float* p = xr + kt * 32;
            const f32x4 lo = *(const f32x4*)p;
            const f32x4 hi = *(const f32x4*)(p + 4);
            short8 a;
            a[0]=(short)f2bf(lo[0]); a[1]=(short)f2bf(lo[1]);
            a[2]=(short)f2bf(lo[2]); a[3]=(short)f2bf(lo[3]);
            a[4]=(short)f2bf(hi[0]); a[5]=(short)f2bf(hi[1]);
            a[6]=(short)f2bf(hi[2]); a[7]=(short)f2bf(hi[3]);
            const unsigned short* wp = lds_w + ((size_t)(kt * 4) * 64 + lane) * 8;
            a0 = __builtin_amdgcn_mfma_f32_16x16x32_bf16(a, *(const short8*)(wp +    0), a0, 0,0,0);
            a1 = __builtin_amdgcn_mfma_f32_16x16x32_bf16(a, *(const short8*)(wp +  512), a1, 0,0,0);
            a2 = __builtin_amdgcn_mfma_f32_16x16x32_bf16(a, *(const short8*)(wp + 1024), a2, 0,0,0);
            a3 = __builtin_amdgcn_mfma_f32_16x16x32_bf16(a, *(const short8*)(wp + 1536), a3, 0,0,0);
        }
        #pragma unroll
        for (int kt = 8; kt < 24; ++kt) {              // h part (bf16 direct)
            const short8 a = *(const short8*)(hr + (size_t)(kt - 8) * 32);
            const unsigned short* wp = lds_w + ((size_t)(kt * 4) * 64 + lane) * 8;
            a0 = __builtin_amdgcn_mfma_f32_16x16x32_bf16(a, *(const short8*)(wp +    0), a0, 0,0,0);
            a1 = __builtin_amdgcn_mfma_f32_16x16x32_bf16(a, *(const short8*)(wp +  512), a1, 0,0,0);
            a2 = __builtin_amdgcn_mfma_f32_16x16x32_bf16(a, *(const short8*)(wp + 1024), a2, 0,0,0);
            a3 = __builtin_amdgcn_mfma_f32_16x16x32_bf16(a, *(const short8*)(wp + 1536), a3, 0,0,0);
        }

        // ---- lane-local LSTM update (gate order i, j, f, o) ----
        unsigned short* hw = hbuf + (size_t)((t + 1) & 1) * (B_DIM * H_DIM);
        #pragma unroll
        for (int j = 0; j < 4; ++j) {
            const float iv = a0[j] + bi;
            const float jv = a1[j] + bj;
            const float fv = a2[j] + bf_;
            const float ov = a3[j] + bo;
            const float cn = sigmoidf_(fv) * c_frag[j] + sigmoidf_(iv) * tanhf_(jv);
            c_frag[j] = cn;
            const float hn = sigmoidf_(ov) * tanhf_(cn);
            hw[(size_t)(orow + j) * H_DIM + hh + lc] = f2bf(hn);
        }

        // ---- per-batch-group barrier (32 blocks), agent scope ----
        __syncthreads();                // all waves' stores drained (vmcnt 0)
        if (tid == 0) {
            __threadfence();            // release: L2 writeback (agent)
            atomicAdd(&bar[bg * 32], 1);
            const int target = 32 * (t + 1);
            while (__hip_atomic_load(&bar[bg * 32], __ATOMIC_RELAXED,
                                     __HIP_MEMORY_SCOPE_AGENT) < target) {
                __builtin_amdgcn_s_sleep(2);
            }
            __threadfence();            // acquire: L1/L2 invalidate
        }
        __syncthreads();
    }
}

// ---------------- final projection: out = h_last @ W_out + b_out ----------------
// grid = ceil(V/128); block 256 (4 waves), wave w owns 32 cols (2 N-tiles).
__global__ void __launch_bounds__(256)
proj_gemm(const unsigned short* __restrict__ h,   // [256][512] bf16 (hbuf[0])
          const float* __restrict__ wout,         // [512][V]
          const float* __restrict__ bout,         // [V]
          float* __restrict__ out)                // [256][V]
{
    const int tid  = threadIdx.x;
    const int w    = tid >> 6;
    const int lane = tid & 63;
    const int lc   = lane & 15;
    const int lk   = lane >> 4;
    const int n0   = blockIdx.x * 128 + w * 32;

    f32x4 acc[16][2];
    #pragma unroll
    for (int mt = 0; mt < 16; ++mt) {
        acc[mt][0] = (f32x4){0.f,0.f,0.f,0.f};
        acc[mt][1] = (f32x4){0.f,0.f,0.f,0.f};
    }
    int ncl[2];
    ncl[0] = min(n0 + lc,      V_DIM - 1);
    ncl[1] = min(n0 + 16 + lc, V_DIM - 1);

    #pragma unroll 4
    for (int kt = 0; kt < 16; ++kt) {
        short8 bfr[2];
        #pragma unroll
        for (int nt = 0; nt < 2; ++nt) {
            #pragma unroll
            for (int j = 0; j < 8; ++j) {
                const int k = kt * 32 + lk * 8 + j;
                bfr[nt][j] = (short)f2bf(wout[(size_t)k * V_DIM + ncl[nt]]);
            }
        }
        #pragma unroll
        for (int mt = 0; mt < 16; ++mt) {
            const short8 a = *(const short8*)(h + (size_t)(mt * 16 + lc) * H_DIM
                                                + kt * 32 + lk * 8);
            acc[mt][0] = __builtin_amdgcn_mfma_f32_16x16x32_bf16(a, bfr[0], acc[mt][0], 0,0,0);
            acc[mt][1] = __builtin_amdgcn_mfma_f32_16x16x32_bf16(a, bfr[1], acc[mt][1], 0,0,0);
        }
    }

    #pragma unroll
    for (int nt = 0; nt < 2; ++nt) {
        const int n = n0 + nt * 16 + lc;
        if (n < V_DIM) {
            const float bb = bout[n];
            #pragma unroll
            for (int mt = 0; mt < 16; ++mt)
                #pragma unroll
                for (int j = 0; j < 4; ++j)
                    out[(size_t)(mt * 16 + lk * 4 + j) * V_DIM + n] = acc[mt][nt][j] + bb;
        }
    }
}

extern "C" void kernel_launch(void* const* d_in, const int* in_sizes, int n_in,
                              void* d_out, int out_size, void* d_ws, size_t ws_size,
                              hipStream_t stream) {
    const float* x    = (const float*)d_in[0];
    const float* wk   = (const float*)d_in[1];
    const float* bias = (const float*)d_in[2];
    const float* wout = (const float*)d_in[3];
    const float* bout = (const float*)d_in[4];
    float* out = (float*)d_out;

    unsigned short* hbuf = (unsigned short*)d_ws;                  // 2*256*512 bf16
    int* bar = (int*)((char*)d_ws + (size_t)2 * B_DIM * H_DIM * 2);

    // init: h0 = 0, barrier counters = 0 (every call — graph-replay safe)
    hipMemsetAsync(hbuf, 0, (size_t)B_DIM * H_DIM * 2, stream);
    hipMemsetAsync(bar, 0, 8 * 32 * sizeof(int), stream);

    hipFuncSetAttribute((const void*)lstm_persist,
                        hipFuncAttributeMaxDynamicSharedMemorySize, 96 * 1024);

    hipLaunchKernelGGL(lstm_persist, dim3(256), dim3(128), 96 * 1024, stream,
                       x, wk, bias, hbuf, bar);
    // after 256 steps, h_last is in hbuf[ T&1 == 0 ]
    hipLaunchKernelGGL(proj_gemm, dim3((V_DIM + 127) / 128), dim3(256), 0, stream,
                       hbuf, wout, bout, out);
}

// Round 2
// 2103.043 us; speedup vs baseline: 1.9854x; 1.9854x over previous
//
#include <hip/hip_runtime.h>
#include <hip/hip_bf16.h>

#define T_DIM 256
#define B_DIM 256
#define E_DIM 256
#define H_DIM 512
#define V_DIM 50257

typedef __attribute__((ext_vector_type(8))) short short8;
typedef __attribute__((ext_vector_type(4))) float f32x4;

__device__ __forceinline__ unsigned short f2bf(float f) {
    union { float f; unsigned u; } v; v.f = f;
    unsigned r = v.u + 0x7FFFu + ((v.u >> 16) & 1u);
    return (unsigned short)(r >> 16);
}
__device__ __forceinline__ short cvt_bf(float f) {
    return (short)f2bf(f);   // compiler fuses pairs into v_cvt_pk_bf16_f32-class code
}
__device__ __forceinline__ float sigmoidf_(float x) {
    return 1.0f / (1.0f + __expf(-x));
}
__device__ __forceinline__ float tanhf_(float x) {
    float xc = fminf(fmaxf(x, -15.0f), 15.0f);
    float e = __expf(2.0f * xc);
    return (e - 1.0f) / (e + 1.0f);
}

// Coherent (MALL) 16B load — bypasses L1/L2 so cross-XCD producer stores
// (done with sc-flagged atomic stores) are always visible. NOTE: the asm
// returns with the load still in flight; a separate s_waitcnt vmcnt(0) +
// sched_barrier(0) must precede any use (rule #18).
__device__ __forceinline__ short8 load_h16(const unsigned short* p) {
    short8 r;
    asm volatile("global_load_dwordx4 %0, %1, off sc0 sc1"
                 : "=v"(r) : "v"(p) : "memory");
    return r;
}

// ---------------- LSTM persistent kernel ----------------
// 256 blocks = 8 batch-groups (32 rows) x 32 hidden-groups (16 cols).
// 128 threads = 2 waves; wave w handles batch rows [bb+w*16, +16).
// Weights slice [768, 4x16] pre-staged once in LDS as B-fragments (96 KiB).
// Cross-block h exchange + barrier entirely via MALL-coherent accesses:
// NO __threadfence (no buffer_wbl2/buffer_inv full-cache walks per step).
__global__ void __launch_bounds__(128, 1)
lstm_persist(const float* __restrict__ x,
             const float* __restrict__ wk,
             const float* __restrict__ bias,
             unsigned short* __restrict__ hbuf,   // [2][B][H] bf16
             int* __restrict__ bar)               // 8 counters, stride 32 ints
{
    extern __shared__ unsigned short lds_w[];     // [96 frag][64 lane][8]
    const int tid = threadIdx.x;
    const int blk = blockIdx.x;
    const int bg  = blk & 7;          // batch group (same-XCD heuristic for x reuse)
    const int hg  = blk >> 3;         // hidden group
    const int bb  = bg * 32;
    const int hh  = hg * 16;

    // ---- preload weights into LDS in B-frag layout (once) ----
    for (int f = 0; f < 96; ++f) {
        const int kt = f >> 2, g = f & 3;
        for (int idx = tid; idx < 512; idx += 128) {
            const int c  = idx & 15;
            const int hi = (idx >> 4) & 3;
            const int j  = idx >> 6;
            const int k  = kt * 32 + hi * 8 + j;
            const int col = g * 512 + hh + c;
            lds_w[(f * 64 + hi * 16 + c) * 8 + j] = f2bf(wk[(size_t)k * 2048 + col]);
        }
    }
    __syncthreads();

    const int w    = tid >> 6;        // wave = M-half
    const int lane = tid & 63;
    const int lc   = lane & 15;
    const int lk   = lane >> 4;

    const float bi  = bias[0 * 512 + hh + lc];
    const float bj  = bias[1 * 512 + hh + lc];
    const float bf_ = bias[2 * 512 + hh + lc] + 1.0f;   // FORGET_BIAS
    const float bo  = bias[3 * 512 + hh + lc];

    f32x4 c_frag = {0.f, 0.f, 0.f, 0.f};

    const int arow = bb + w * 16 + lc;                 // A-frag row (load side)
    const int orow = bb + w * 16 + lk * 4;             // C-frag row base (store side)
    const float* xbase = x + (size_t)arow * E_DIM + lk * 8;
    int* cnt = &bar[bg * 32];

    for (int t = 0; t < T_DIM; ++t) {
        // ---- 1. issue coherent h loads early (latency hides under x part) ----
        short8 hfr[16];
        if (t > 0) {
            const unsigned short* hr = hbuf + (size_t)(t & 1) * (B_DIM * H_DIM)
                                            + (size_t)arow * H_DIM + lk * 8;
            #pragma unroll
            for (int k = 0; k < 16; ++k)
                hfr[k] = load_h16(hr + k * 32);
        }

        // ---- 2. x part (fp32 -> bf16, cached loads) ----
        f32x4 a0 = {0.f,0.f,0.f,0.f}, a1 = a0, a2 = a0, a3 = a0;
        const float* xr = xbase + (size_t)t * (B_DIM * E_DIM);
        #pragma unroll
        for (int kt = 0; kt < 8; ++kt) {
            const float* p = xr + kt * 32;
            const f32x4 lo = *(const f32x4*)p;
            const f32x4 hi = *(const f32x4*)(p + 4);
            short8 a;
            a[0]=cvt_bf(lo[0]); a[1]=cvt_bf(lo[1]); a[2]=cvt_bf(lo[2]); a[3]=cvt_bf(lo[3]);
            a[4]=cvt_bf(hi[0]); a[5]=cvt_bf(hi[1]); a[6]=cvt_bf(hi[2]); a[7]=cvt_bf(hi[3]);
            const unsigned short* wp = lds_w + ((size_t)(kt * 4) * 64 + lane) * 8;
            a0 = __builtin_amdgcn_mfma_f32_16x16x32_bf16(a, *(const short8*)(wp +    0), a0, 0,0,0);
            a1 = __builtin_amdgcn_mfma_f32_16x16x32_bf16(a, *(const short8*)(wp +  512), a1, 0,0,0);
            a2 = __builtin_amdgcn_mfma_f32_16x16x32_bf16(a, *(const short8*)(wp + 1024), a2, 0,0,0);
            a3 = __builtin_amdgcn_mfma_f32_16x16x32_bf16(a, *(const short8*)(wp + 1536), a3, 0,0,0);
        }

        // ---- 3. h part ----
        if (t > 0) {
            asm volatile("s_waitcnt vmcnt(0)" ::: "memory");
            __builtin_amdgcn_sched_barrier(0);
            #pragma unroll
            for (int k = 0; k < 16; ++k) {
                const unsigned short* wp = lds_w + ((size_t)((8 + k) * 4) * 64 + lane) * 8;
                a0 = __builtin_amdgcn_mfma_f32_16x16x32_bf16(hfr[k], *(const short8*)(wp +    0), a0, 0,0,0);
                a1 = __builtin_amdgcn_mfma_f32_16x16x32_bf16(hfr[k], *(const short8*)(wp +  512), a1, 0,0,0);
                a2 = __builtin_amdgcn_mfma_f32_16x16x32_bf16(hfr[k], *(const short8*)(wp + 1024), a2, 0,0,0);
                a3 = __builtin_amdgcn_mfma_f32_16x16x32_bf16(hfr[k], *(const short8*)(wp + 1536), a3, 0,0,0);
            }
        }

        // ---- 4. lane-local LSTM update (gate order i, j, f, o) ----
        unsigned short* hw = hbuf + (size_t)((t + 1) & 1) * (B_DIM * H_DIM);
        #pragma unroll
        for (int j = 0; j < 4; ++j) {
            const float iv = a0[j] + bi;
            const float jv = a1[j] + bj;
            const float fv = a2[j] + bf_;
            const float ov = a3[j] + bo;
            const float cn = sigmoidf_(fv) * c_frag[j] + sigmoidf_(iv) * tanhf_(jv);
            c_frag[j] = cn;
            const float hn = sigmoidf_(ov) * tanhf_(cn);
            // agent-scope relaxed store: write-through to the coherent point
            __hip_atomic_store(&hw[(size_t)(orow + j) * H_DIM + hh + lc],
                               f2bf(hn), __ATOMIC_RELAXED, __HIP_MEMORY_SCOPE_AGENT);
        }

        // ---- 5. per-batch-group barrier (32 blocks) — no cache-wide ops ----
        __syncthreads();                // emits s_waitcnt vmcnt(0): release (stores at MALL)
        if (tid == 0) {
            __hip_atomic_fetch_add(cnt, 1, __ATOMIC_RELAXED, __HIP_MEMORY_SCOPE_AGENT);
            const int target = 32 * (t + 1);
            while (__hip_atomic_load(cnt, __ATOMIC_RELAXED,
                                     __HIP_MEMORY_SCOPE_AGENT) < target) {
                __builtin_amdgcn_s_sleep(1);
            }
        }
        __syncthreads();
    }
}

// ---------------- final projection: out = h_last @ W_out + b_out ----------------
__global__ void __launch_bounds__(256)
proj_gemm(const unsigned short* __restrict__ h,   // [256][512] bf16 (hbuf[0])
          const float* __restrict__ wout,         // [512][V]
          const float* __restrict__ bout,         // [V]
          float* __restrict__ out)                // [256][V]
{
    const int tid  = threadIdx.x;
    const int w    = tid >> 6;
    const int lane = tid & 63;
    const int lc   = lane & 15;
    const int lk   = lane >> 4;
    const int n0   = blockIdx.x * 128 + w * 32;

    f32x4 acc[16][2];
    #pragma unroll
    for (int mt = 0; mt < 16; ++mt) {
        acc[mt][0] = (f32x4){0.f,0.f,0.f,0.f};
        acc[mt][1] = (f32x4){0.f,0.f,0.f,0.f};
    }
    int ncl[2];
    ncl[0] = min(n0 + lc,      V_DIM - 1);
    ncl[1] = min(n0 + 16 + lc, V_DIM - 1);

    #pragma unroll 4
    for (int kt = 0; kt < 16; ++kt) {
        short8 bfr[2];
        #pragma unroll
        for (int nt = 0; nt < 2; ++nt) {
            #pragma unroll
            for (int j = 0; j < 8; ++j) {
                const int k = kt * 32 + lk * 8 + j;
                bfr[nt][j] = (short)f2bf(wout[(size_t)k * V_DIM + ncl[nt]]);
            }
        }
        #pragma unroll
        for (int mt = 0; mt < 16; ++mt) {
            const short8 a = *(const short8*)(h + (size_t)(mt * 16 + lc) * H_DIM
                                                + kt * 32 + lk * 8);
            acc[mt][0] = __builtin_amdgcn_mfma_f32_16x16x32_bf16(a, bfr[0], acc[mt][0], 0,0,0);
            acc[mt][1] = __builtin_amdgcn_mfma_f32_16x16x32_bf16(a, bfr[1], acc[mt][1], 0,0,0);
        }
    }

    #pragma unroll
    for (int nt = 0; nt < 2; ++nt) {
        const int n = n0 + nt * 16 + lc;
        if (n < V_DIM) {
            const float bb = bout[n];
            #pragma unroll
            for (int mt = 0; mt < 16; ++mt)
                #pragma unroll
                for (int j = 0; j < 4; ++j)
                    out[(size_t)(mt * 16 + lk * 4 + j) * V_DIM + n] = acc[mt][nt][j] + bb;
        }
    }
}

extern "C" void kernel_launch(void* const* d_in, const int* in_sizes, int n_in,
                              void* d_out, int out_size, void* d_ws, size_t ws_size,
                              hipStream_t stream) {
    const float* x    = (const float*)d_in[0];
    const float* wk   = (const float*)d_in[1];
    const float* bias = (const float*)d_in[2];
    const float* wout = (const float*)d_in[3];
    const float* bout = (const float*)d_in[4];
    float* out = (float*)d_out;

    unsigned short* hbuf = (unsigned short*)d_ws;                  // 2*256*512 bf16
    int* bar = (int*)((char*)d_ws + (size_t)2 * B_DIM * H_DIM * 2);

    // barrier counters = 0 every call (graph-replay safe). hbuf needs no init:
    // t=0 skips the h-GEMM (h0 == 0) and fully writes hbuf[1].
    hipMemsetAsync(bar, 0, 8 * 32 * sizeof(int), stream);

    hipFuncSetAttribute((const void*)lstm_persist,
                        hipFuncAttributeMaxDynamicSharedMemorySize, 96 * 1024);

    hipLaunchKernelGGL(lstm_persist, dim3(256), dim3(128), 96 * 1024, stream,
                       x, wk, bias, hbuf, bar);
    // after 256 steps, h_last is in hbuf[0]
    hipLaunchKernelGGL(proj_gemm, dim3((V_DIM + 127) / 128), dim3(256), 0, stream,
                       hbuf, wout, bout, out);
}

// Round 3
// 1688.256 us; speedup vs baseline: 2.4732x; 1.2457x over previous
//
#include <hip/hip_runtime.h>
#include <hip/hip_bf16.h>

#define T_DIM 256
#define B_DIM 256
#define E_DIM 256
#define H_DIM 512
#define V_DIM 50257

typedef __attribute__((ext_vector_type(8))) short short8;
typedef __attribute__((ext_vector_type(4))) float f32x4;

__device__ __forceinline__ unsigned short f2bf(float f) {
    union { float f; unsigned u; } v; v.f = f;
    unsigned r = v.u + 0x7FFFu + ((v.u >> 16) & 1u);
    return (unsigned short)(r >> 16);
}
__device__ __forceinline__ short cvt_bf(float f) { return (short)f2bf(f); }
__device__ __forceinline__ float sigmoidf_(float x) {
    return 1.0f / (1.0f + __expf(-x));
}
__device__ __forceinline__ float tanhf_(float x) {
    float xc = fminf(fmaxf(x, -15.0f), 15.0f);
    float e = __expf(2.0f * xc);
    return (e - 1.0f) / (e + 1.0f);
}

// Coherent (MALL) accesses — bypass L1/L2 so cross-XCD traffic meets at the
// memory-side cache. Loads return with the op still in flight; callers must
// s_waitcnt vmcnt(N) + sched_barrier(0) before use (rule #18).
__device__ __forceinline__ short8 load_h16(const unsigned short* p) {
    short8 r;
    asm volatile("global_load_dwordx4 %0, %1, off sc0 sc1"
                 : "=v"(r) : "v"(p) : "memory");
    return r;
}
__device__ __forceinline__ int load_flag(const int* p) {
    int r;
    asm volatile("global_load_dword %0, %1, off sc0 sc1\n\t"
                 "s_waitcnt vmcnt(0)"
                 : "=v"(r) : "v"(p) : "memory");
    return r;
}
__device__ __forceinline__ void store_h2(unsigned short* p, unsigned short v) {
    asm volatile("global_store_short %0, %1, off sc0 sc1"
                 :: "v"(p), "v"((unsigned)v) : "memory");
}
__device__ __forceinline__ void store_flag(int* p, int v) {
    asm volatile("global_store_dword %0, %1, off sc0 sc1"
                 :: "v"(p), "v"(v) : "memory");
}

// ---------------- LSTM persistent kernel ----------------
// 256 blocks = 8 batch-groups (32 rows) x 32 hidden-groups (16 cols).
// 128 threads = 2 waves; wave w handles batch rows [bb+w*16, +16).
// Weights slice [768, 4x16] staged once in LDS as B-fragments (96 KiB).
// Sync: per-producer epoch flags (64B-spaced, no RMW); x-part GEMM runs
// BEFORE the flag wait so producer arrival spread hides under compute.
__global__ void __launch_bounds__(128, 1)
lstm_persist(const float* __restrict__ x,
             const float* __restrict__ wk,
             const float* __restrict__ bias,
             unsigned short* __restrict__ hbuf,   // [2][B][H] bf16
             int* __restrict__ flags)             // [8][32] epochs, 16-int stride
{
    extern __shared__ unsigned short lds_w[];     // [96 frag][64 lane][8]
    const int tid = threadIdx.x;
    const int blk = blockIdx.x;
    const int bg  = blk & 7;          // batch group (blk%8 -> same-XCD heuristic)
    const int hg  = blk >> 3;         // hidden group
    const int bb  = bg * 32;
    const int hh  = hg * 16;

    // ---- preload weights into LDS in B-frag layout (once) ----
    for (int f = 0; f < 96; ++f) {
        const int kt = f >> 2, g = f & 3;
        for (int idx = tid; idx < 512; idx += 128) {
            const int c  = idx & 15;
            const int hi = (idx >> 4) & 3;
            const int j  = idx >> 6;
            const int k  = kt * 32 + hi * 8 + j;
            const int col = g * 512 + hh + c;
            lds_w[(f * 64 + hi * 16 + c) * 8 + j] = f2bf(wk[(size_t)k * 2048 + col]);
        }
    }
    __syncthreads();

    const int w    = tid >> 6;        // wave = M-half
    const int lane = tid & 63;
    const int lc   = lane & 15;
    const int lk   = lane >> 4;

    const float bi  = bias[0 * 512 + hh + lc];
    const float bj  = bias[1 * 512 + hh + lc];
    const float bf_ = bias[2 * 512 + hh + lc] + 1.0f;   // FORGET_BIAS
    const float bo  = bias[3 * 512 + hh + lc];

    f32x4 c_frag = {0.f, 0.f, 0.f, 0.f};

    const int arow = bb + w * 16 + lc;                 // A-frag row (load side)
    const int orow = bb + w * 16 + lk * 4;             // C-frag row base (store side)
    const float* xbase = x + (size_t)arow * E_DIM + lk * 8;

    int* fgrp = flags + bg * 512;                      // 32 flags, 64B apart
    const int* fpoll = fgrp + (lane & 31) * 16;        // one flag per lane
    int* fmine = fgrp + hg * 16;

    for (int t = 0; t < T_DIM; ++t) {
        // ---- 1. x part first (independent of h_t) ----
        f32x4 a0 = {0.f,0.f,0.f,0.f}, a1 = a0, a2 = a0, a3 = a0;
        const float* xr = xbase + (size_t)t * (B_DIM * E_DIM);
        #pragma unroll
        for (int kt = 0; kt < 8; ++kt) {
            const float* p = xr + kt * 32;
            const f32x4 lo = *(const f32x4*)p;
            const f32x4 hi = *(const f32x4*)(p + 4);
            short8 a;
            a[0]=cvt_bf(lo[0]); a[1]=cvt_bf(lo[1]); a[2]=cvt_bf(lo[2]); a[3]=cvt_bf(lo[3]);
            a[4]=cvt_bf(hi[0]); a[5]=cvt_bf(hi[1]); a[6]=cvt_bf(hi[2]); a[7]=cvt_bf(hi[3]);
            const unsigned short* wp = lds_w + ((size_t)(kt * 4) * 64 + lane) * 8;
            a0 = __builtin_amdgcn_mfma_f32_16x16x32_bf16(a, *(const short8*)(wp +    0), a0, 0,0,0);
            a1 = __builtin_amdgcn_mfma_f32_16x16x32_bf16(a, *(const short8*)(wp +  512), a1, 0,0,0);
            a2 = __builtin_amdgcn_mfma_f32_16x16x32_bf16(a, *(const short8*)(wp + 1024), a2, 0,0,0);
            a3 = __builtin_amdgcn_mfma_f32_16x16x32_bf16(a, *(const short8*)(wp + 1536), a3, 0,0,0);
        }

        // ---- 2. wait for all 32 producers of h_t (parallel per-lane poll) ----
        if (t > 0) {
            while (load_flag(fpoll) < t)
                __builtin_amdgcn_s_sleep(1);
            __builtin_amdgcn_sched_barrier(0);

            // ---- 3. h loads (coherent), drained in two halves ----
            const unsigned short* hr = hbuf + (size_t)(t & 1) * (B_DIM * H_DIM)
                                            + (size_t)arow * H_DIM + lk * 8;
            short8 hfr[16];
            #pragma unroll
            for (int k = 0; k < 16; ++k)
                hfr[k] = load_h16(hr + k * 32);

            asm volatile("s_waitcnt vmcnt(8)" ::: "memory");
            __builtin_amdgcn_sched_barrier(0);
            #pragma unroll
            for (int k = 0; k < 8; ++k) {
                const unsigned short* wp = lds_w + ((size_t)((8 + k) * 4) * 64 + lane) * 8;
                a0 = __builtin_amdgcn_mfma_f32_16x16x32_bf16(hfr[k], *(const short8*)(wp +    0), a0, 0,0,0);
                a1 = __builtin_amdgcn_mfma_f32_16x16x32_bf16(hfr[k], *(const short8*)(wp +  512), a1, 0,0,0);
                a2 = __builtin_amdgcn_mfma_f32_16x16x32_bf16(hfr[k], *(const short8*)(wp + 1024), a2, 0,0,0);
                a3 = __builtin_amdgcn_mfma_f32_16x16x32_bf16(hfr[k], *(const short8*)(wp + 1536), a3, 0,0,0);
            }
            asm volatile("s_waitcnt vmcnt(0)" ::: "memory");
            __builtin_amdgcn_sched_barrier(0);
            #pragma unroll
            for (int k = 8; k < 16; ++k) {
                const unsigned short* wp = lds_w + ((size_t)((8 + k) * 4) * 64 + lane) * 8;
                a0 = __builtin_amdgcn_mfma_f32_16x16x32_bf16(hfr[k], *(const short8*)(wp +    0), a0, 0,0,0);
                a1 = __builtin_amdgcn_mfma_f32_16x16x32_bf16(hfr[k], *(const short8*)(wp +  512), a1, 0,0,0);
                a2 = __builtin_amdgcn_mfma_f32_16x16x32_bf16(hfr[k], *(const short8*)(wp + 1024), a2, 0,0,0);
                a3 = __builtin_amdgcn_mfma_f32_16x16x32_bf16(hfr[k], *(const short8*)(wp + 1536), a3, 0,0,0);
            }
        }

        // ---- 4. lane-local LSTM update (gate order i, j, f, o) ----
        unsigned short* hw = hbuf + (size_t)((t + 1) & 1) * (B_DIM * H_DIM);
        #pragma unroll
        for (int j = 0; j < 4; ++j) {
            const float iv = a0[j] + bi;
            const float jv = a1[j] + bj;
            const float fv = a2[j] + bf_;
            const float ov = a3[j] + bo;
            const float cn = sigmoidf_(fv) * c_frag[j] + sigmoidf_(iv) * tanhf_(jv);
            c_frag[j] = cn;
            const float hn = sigmoidf_(ov) * tanhf_(cn);
            store_h2(&hw[(size_t)(orow + j) * H_DIM + hh + lc], f2bf(hn));
        }

        // ---- 5. release: drain both waves' stores, then publish epoch ----
        __syncthreads();               // each wave drains vmcnt(0) before s_barrier
        if (tid == 0)
            store_flag(fmine, t + 1);
    }
}

// ---------------- final projection: out = h_last @ W_out + b_out ----------------
__global__ void __launch_bounds__(256)
proj_gemm(const unsigned short* __restrict__ h,   // [256][512] bf16 (hbuf[0])
          const float* __restrict__ wout,         // [512][V]
          const float* __restrict__ bout,         // [V]
          float* __restrict__ out)                // [256][V]
{
    const int tid  = threadIdx.x;
    const int w    = tid >> 6;
    const int lane = tid & 63;
    const int lc   = lane & 15;
    const int lk   = lane >> 4;
    const int n0   = blockIdx.x * 128 + w * 32;

    f32x4 acc[16][2];
    #pragma unroll
    for (int mt = 0; mt < 16; ++mt) {
        acc[mt][0] = (f32x4){0.f,0.f,0.f,0.f};
        acc[mt][1] = (f32x4){0.f,0.f,0.f,0.f};
    }
    int ncl[2];
    ncl[0] = min(n0 + lc,      V_DIM - 1);
    ncl[1] = min(n0 + 16 + lc, V_DIM - 1);

    #pragma unroll 4
    for (int kt = 0; kt < 16; ++kt) {
        short8 bfr[2];
        #pragma unroll
        for (int nt = 0; nt < 2; ++nt) {
            #pragma unroll
            for (int j = 0; j < 8; ++j) {
                const int k = kt * 32 + lk * 8 + j;
                bfr[nt][j] = (short)f2bf(wout[(size_t)k * V_DIM + ncl[nt]]);
            }
        }
        #pragma unroll
        for (int mt = 0; mt < 16; ++mt) {
            const short8 a = *(const short8*)(h + (size_t)(mt * 16 + lc) * H_DIM
                                                + kt * 32 + lk * 8);
            acc[mt][0] = __builtin_amdgcn_mfma_f32_16x16x32_bf16(a, bfr[0], acc[mt][0], 0,0,0);
            acc[mt][1] = __builtin_amdgcn_mfma_f32_16x16x32_bf16(a, bfr[1], acc[mt][1], 0,0,0);
        }
    }

    #pragma unroll
    for (int nt = 0; nt < 2; ++nt) {
        const int n = n0 + nt * 16 + lc;
        if (n < V_DIM) {
            const float bb = bout[n];
            #pragma unroll
            for (int mt = 0; mt < 16; ++mt)
                #pragma unroll
                for (int j = 0; j < 4; ++j)
                    out[(size_t)(mt * 16 + lk * 4 + j) * V_DIM + n] = acc[mt][nt][j] + bb;
        }
    }
}

extern "C" void kernel_launch(void* const* d_in, const int* in_sizes, int n_in,
                              void* d_out, int out_size, void* d_ws, size_t ws_size,
                              hipStream_t stream) {
    const float* x    = (const float*)d_in[0];
    const float* wk   = (const float*)d_in[1];
    const float* bias = (const float*)d_in[2];
    const float* wout = (const float*)d_in[3];
    const float* bout = (const float*)d_in[4];
    float* out = (float*)d_out;

    unsigned short* hbuf = (unsigned short*)d_ws;                  // 2*256*512 bf16
    int* flags = (int*)((char*)d_ws + (size_t)2 * B_DIM * H_DIM * 2);

    // flags = 0 every call (graph-replay safe). hbuf needs no init:
    // t=0 skips the h-GEMM (h0 == 0) and fully writes hbuf[1].
    hipMemsetAsync(flags, 0, 8 * 512 * sizeof(int), stream);

    hipFuncSetAttribute((const void*)lstm_persist,
                        hipFuncAttributeMaxDynamicSharedMemorySize, 96 * 1024);

    hipLaunchKernelGGL(lstm_persist, dim3(256), dim3(128), 96 * 1024, stream,
                       x, wk, bias, hbuf, flags);
    // after 256 steps, h_last is in hbuf[0]
    hipLaunchKernelGGL(proj_gemm, dim3((V_DIM + 127) / 128), dim3(256), 0, stream,
                       hbuf, wout, bout, out);
}